// Round 17
// baseline (2291.596 us; speedup 1.0000x reference)
//
#include <hip/hip_runtime.h>
#include <hip/hip_bf16.h>
#include <hip/hip_fp16.h>

#define E_ 16
#define T_ 128

typedef _Float16 h2_t __attribute__((ext_vector_type(2)));
typedef _Float16 half4_t __attribute__((ext_vector_type(4)));
typedef _Float16 half8_t __attribute__((ext_vector_type(8)));
typedef float f32x4 __attribute__((ext_vector_type(4)));

__device__ __forceinline__ float apply_act(float v, int act) {
  if (act == 1) return tanhf(v);
  if (act == 2) { // jax.nn.gelu approximate=True
    const float c = 0.7978845608028654f;
    return 0.5f * v * (1.0f + tanhf(c * (v + 0.044715f * v * v * v)));
  }
  return v;
}

// ---- MFMA GEMM (unchanged from round 12, verified passing) ----
template<int NT>
__global__ void __launch_bounds__(256) gemm_mfma(
    const float* __restrict__ A, const float* __restrict__ W,
    const float* __restrict__ bias, float* __restrict__ C, float* __restrict__ part,
    int N, int K, int lda, int ldc,
    long sAe, long sWe, long sBe, long sCe,
    int S, int act)
{
  int n0 = blockIdx.x * (32 * NT);
  int e  = blockIdx.y;
  int s  = blockIdx.z;
  const float* Ae = A + (long)e * sAe;
  const float* We = W + (long)e * sWe;
  int kper = K / S;
  int kb = s * kper, ke2 = kb + kper;

  __shared__ _Float16 As[128 * 40];   // 10,240 B

  int tid  = threadIdx.x;
  int lane = tid & 63;
  int w    = tid >> 6;
  int wm   = (w >> 1) * 64;
  int wn   = (w & 1) * (16 * NT);
  int l16  = lane & 15;
  int lk   = lane >> 4;

  f32x4 acc[4][NT];
  #pragma unroll
  for (int i = 0; i < 4; ++i)
    #pragma unroll
    for (int j = 0; j < NT; ++j)
      acc[i][j] = (f32x4){0.f, 0.f, 0.f, 0.f};

  for (int k0 = kb; k0 < ke2; k0 += 32) {
    __syncthreads();
    #pragma unroll
    for (int i = 0; i < 4; ++i) {
      int idx = tid + 256 * i;
      int row = idx >> 3, k4 = idx & 7;
      float4 a4 = *(const float4*)(Ae + (long)row * lda + k0 + k4 * 4);
      half4_t hv;
      hv.x = (_Float16)a4.x; hv.y = (_Float16)a4.y;
      hv.z = (_Float16)a4.z; hv.w = (_Float16)a4.w;
      *(half4_t*)(&As[row * 40 + k4 * 4]) = hv;
    }
    __syncthreads();
    #pragma unroll
    for (int nt = 0; nt < NT; ++nt) {
      int ncol = n0 + wn + nt * 16 + l16;
      const float* Wc = We + (long)(k0 + lk * 8) * N + ncol;
      half8_t b;
      #pragma unroll
      for (int j = 0; j < 8; ++j) b[j] = (_Float16)Wc[(long)j * N];
      #pragma unroll
      for (int mt = 0; mt < 4; ++mt) {
        half8_t a = *(const half8_t*)(&As[(wm + mt * 16 + l16) * 40 + lk * 8]);
        acc[mt][nt] = __builtin_amdgcn_mfma_f32_16x16x32_f16(a, b, acc[mt][nt], 0, 0, 0);
      }
    }
  }

  if (S == 1) {
    #pragma unroll
    for (int mt = 0; mt < 4; ++mt)
      #pragma unroll
      for (int nt = 0; nt < NT; ++nt) {
        int col = n0 + wn + nt * 16 + l16;
        float bv = bias[(long)e * sBe + col];
        #pragma unroll
        for (int r = 0; r < 4; ++r) {
          int row = wm + mt * 16 + lk * 4 + r;
          C[(long)e * sCe + (long)row * ldc + col] = apply_act(acc[mt][nt][r] + bv, act);
        }
      }
  } else {
    float* pp = part + ((long)(s * gridDim.y + e) * 128) * N;
    #pragma unroll
    for (int mt = 0; mt < 4; ++mt)
      #pragma unroll
      for (int nt = 0; nt < NT; ++nt) {
        int col = n0 + wn + nt * 16 + l16;
        #pragma unroll
        for (int r = 0; r < 4; ++r) {
          int row = wm + mt * 16 + lk * 4 + r;
          pp[(long)row * N + col] = acc[mt][nt][r];
        }
      }
  }
}

// reduce split-K partials + bias + act -> C (unchanged)
__global__ void __launch_bounds__(256) reduce_ep(
    const float* __restrict__ part, const float* __restrict__ bias, float* __restrict__ C,
    int S, int N, int ldc, long sBe, long sCe, int act, int total, int Eb)
{
  int idx = blockIdx.x * 256 + threadIdx.x;
  if (idx >= total) return;
  int n = idx % N;
  int r = (idx / N) & 127;
  int e = idx / (N * 128);
  long sstride = (long)Eb * 128 * N;
  float v = 0.f;
  for (int s = 0; s < S; ++s) v += part[s * sstride + ((long)e * 128 + r) * N + n];
  v = apply_act(v + bias[(long)e * sBe + n], act);
  C[(long)e * sCe + (long)r * ldc + n] = v;
}

// ---- sequential RNN layer: h[t] = tanh(P[t] + h[t-1] @ Wh) -- MFMA+AGPR ----
// Synthesis of the two validated halves:
//  * R15 (passed): replicated-A MFMA trick -- broadcast h as all 16 A-rows,
//    weights as B-frags, D-rows replicated; fragment mappings = gemm_mfma's.
//  * R16 (passed): at block=512 the caps are friendly -- 128 arch VGPRs
//    honored, AGPRs allocate on top (224 total worked).
// Geometry: ONE workgroup per encoder, 512 threads = 8 waves; wave w owns
// cols [64w, 64w+64) over the FULL K=512 -> 64 B-frags/thread, ALL pinned
// in AGPRs = 256 AGPRs (encoding max; pool audit at 2 waves/SIMD:
// 2 x (256 + ~44 arch) = 600 <= 2048 regs/SIMD). Arch side: 4 f32x4 acc +
// temps ~= 44 <= 128 cap -> zero spill, nothing in LDS but the 1 KB hbuf.
// Per step: 16 broadcast ds_read_b128 of h (4 distinct addrs/wave) +
// 64 MFMAs/wave (matvec on the MATRIX pipe -- the VALU design was capped at
// ~1 us/step by rdlane dependency chains: R12 295, R16 438 us/layer) +
// tanh/writes on lanes<16 + 2 barriers ~= 1100-1300 cyc ~= 0.5 us/step.
__global__ void
__attribute__((amdgpu_flat_work_group_size(512, 512)))
rnn_seq(
    const float* __restrict__ P,     // [T][E][512], pre-activation incl. bias
    const float* __restrict__ Wh,    // + e*sWe : [512][512]
    float* __restrict__ H,           // (t*E+e)*1536 + col (layer offset by caller)
    long sWe)
{
  __shared__ _Float16 hbuf[512];     // 1 KB: h(t-1) fp16

  int tid  = threadIdx.x;
  int lane = tid & 63;
  int w    = tid >> 6;               // wave 0..7
  int l16  = lane & 15;
  int lk   = lane >> 4;              // 0..3
  int e    = blockIdx.x;
  int colbase = w * 64;

  const float* W = Wh + (long)e * sWe;   // element (k,c) at W[k*512 + c]

  // B-frag (ct, kt): col = colbase + ct*16 + l16, k = kt*32 + lk*8 + j
  half8_t bf0[16], bf1[16], bf2[16], bf3[16];
  #pragma unroll
  for (int kt = 0; kt < 16; ++kt) {
    const float* Wc = W + (long)(kt * 32 + lk * 8) * 512 + colbase + l16;
    half8_t b0, b1, b2, b3;
    #pragma unroll
    for (int j = 0; j < 8; ++j) {
      b0[j] = (_Float16)Wc[(long)j * 512];
      b1[j] = (_Float16)Wc[(long)j * 512 + 16];
      b2[j] = (_Float16)Wc[(long)j * 512 + 32];
      b3[j] = (_Float16)Wc[(long)j * 512 + 48];
    }
    bf0[kt] = b0; asm("" : "+a"(bf0[kt]));
    bf1[kt] = b1; asm("" : "+a"(bf1[kt]));
    bf2[kt] = b2; asm("" : "+a"(bf2[kt]));
    bf3[kt] = b3; asm("" : "+a"(bf3[kt]));
  }
  if (tid < 256) ((uint32_t*)hbuf)[tid] = 0;   // h(-1) = 0
  __syncthreads();

  for (int t = 0; t < T_; ++t) {
    float p0 = 0.f, p1 = 0.f, p2 = 0.f, p3 = 0.f;
    if (lane < 16) {
      const float* Pp = P + ((long)t * E_ + e) * 512 + colbase + lane;
      p0 = Pp[0]; p1 = Pp[16]; p2 = Pp[32]; p3 = Pp[48];
    }
    f32x4 a0 = {0.f,0.f,0.f,0.f}, a1 = {0.f,0.f,0.f,0.f};
    f32x4 a2 = {0.f,0.f,0.f,0.f}, a3 = {0.f,0.f,0.f,0.f};
    #pragma unroll
    for (int kt = 0; kt < 16; ++kt) {
      // broadcast h-fragment: addr depends only on lk -> all 16 A rows = h
      half8_t a = *(const half8_t*)(&hbuf[kt * 32 + lk * 8]);
      a0 = __builtin_amdgcn_mfma_f32_16x16x32_f16(a, bf0[kt], a0, 0, 0, 0);
      a1 = __builtin_amdgcn_mfma_f32_16x16x32_f16(a, bf1[kt], a1, 0, 0, 0);
      a2 = __builtin_amdgcn_mfma_f32_16x16x32_f16(a, bf2[kt], a2, 0, 0, 0);
      a3 = __builtin_amdgcn_mfma_f32_16x16x32_f16(a, bf3[kt], a3, 0, 0, 0);
    }
    __syncthreads();                 // all hbuf reads complete before rewrite
    if (lane < 16) {
      // D rows replicated (all A rows = h); reg 0 holds y[col]
      float v0 = tanhf(a0[0] + p0);
      float v1 = tanhf(a1[0] + p1);
      float v2 = tanhf(a2[0] + p2);
      float v3 = tanhf(a3[0] + p3);
      int col = colbase + lane;
      float* Hp = H + ((long)t * E_ + e) * 1536;
      Hp[col] = v0; Hp[col + 16] = v1; Hp[col + 32] = v2; Hp[col + 48] = v3;
      hbuf[col]      = (_Float16)v0;
      hbuf[col + 16] = (_Float16)v1;
      hbuf[col + 32] = (_Float16)v2;
      hbuf[col + 48] = (_Float16)v3;
    }
    __syncthreads();                 // new h visible for next step
  }
}

extern "C" void kernel_launch(void* const* d_in, const int* in_sizes, int n_in,
                              void* d_out, int out_size, void* d_ws, size_t ws_size,
                              hipStream_t stream)
{
  const float* x      = (const float*)d_in[0];
  const float* W_in0  = (const float*)d_in[1];
  const float* Wh0    = (const float*)d_in[2];
  const float* b0     = (const float*)d_in[3];
  const float* W_inr  = (const float*)d_in[4];
  const float* Wh_r   = (const float*)d_in[5];
  const float* b_r    = (const float*)d_in[6];
  const float* W_ff1  = (const float*)d_in[7];
  const float* b_ff1  = (const float*)d_in[8];
  const float* W_ff2  = (const float*)d_in[9];
  const float* b_ff2  = (const float*)d_in[10];
  const float* W_d0   = (const float*)d_in[11];
  const float* b_d0   = (const float*)d_in[12];
  const float* W_dmid = (const float*)d_in[13];
  const float* b_dmid = (const float*)d_in[14];
  const float* W_dout = (const float*)d_in[15];
  const float* b_dout = (const float*)d_in[16];
  float* ws = (float*)d_ws;

  // workspace layout (floats)
  float* h    = ws;                    // [T][E][3][512]  3,145,728
  float* P    = ws + 3145728;          // [T][E][512]     1,048,576
  float* FF   = ws + 4194304;          // [T][E][2048]    4,194,304
  float* ENC  = ws + 8388608;          // [T][E*512]      1,048,576
  float* Z0   = ws + 9437184;          // [128][2048]       262,144
  float* Z1   = ws + 9699328;
  float* Z2   = ws + 9961472;
  float* PART = ws + 10223616;         // split-K partials 2,097,152

  (void)in_sizes; (void)n_in; (void)out_size; (void)ws_size;

  dim3 blk(256);

  // P = x @ W_in0 + b0
  gemm_mfma<2><<<dim3(8,16,1), blk, 0, stream>>>(x, W_in0, b0, P, PART,
      512, 32, 32, 8192, 0L, 16384L, 512L, 512L, 1, 0);
  // layer 0 recurrence
  rnn_seq<<<dim3(16), dim3(512), 0, stream>>>(P, Wh0, h, 262144L);
  // P = h0 @ W_in_rest[:,0] + b_rest[:,0]
  gemm_mfma<1><<<dim3(16,16,1), blk, 0, stream>>>(h, W_inr, b_r, P, PART,
      512, 512, 24576, 8192, 1536L, 524288L, 1024L, 512L, 1, 0);
  rnn_seq<<<dim3(16), dim3(512), 0, stream>>>(P, Wh_r, h + 512, 524288L);
  // P = h1 @ W_in_rest[:,1] + b_rest[:,1]
  gemm_mfma<1><<<dim3(16,16,1), blk, 0, stream>>>(h + 512, W_inr + 262144, b_r + 512, P, PART,
      512, 512, 24576, 8192, 1536L, 524288L, 1024L, 512L, 1, 0);
  rnn_seq<<<dim3(16), dim3(512), 0, stream>>>(P, Wh_r + 262144, h + 1024, 524288L);
  // FF1: gelu(cat @ W_ff1 + b_ff1) — 512 blocks = 2 WG/CU
  gemm_mfma<2><<<dim3(32,16,1), blk, 0, stream>>>(h, W_ff1, b_ff1, FF, PART,
      2048, 1536, 24576, 32768, 1536L, 3145728L, 2048L, 2048L, 1, 2);
  // FF2 (split-2): ENC = FF @ W_ff2 + b_ff2 — 512 blocks
  gemm_mfma<1><<<dim3(16,16,2), blk, 0, stream>>>(FF, W_ff2, b_ff2, ENC, PART,
      512, 2048, 32768, 8192, 2048L, 1048576L, 512L, 512L, 2, 0);
  reduce_ep<<<dim3(4096), blk, 0, stream>>>(PART, b_ff2, ENC,
      2, 512, 8192, 512L, 512L, 0, 16*128*512, 16);
  // decoder: Z0 = tanh(ENC @ W_d0 + b_d0)   (split-8)
  gemm_mfma<2><<<dim3(32,1,8), blk, 0, stream>>>(ENC, W_d0, b_d0, Z0, PART,
      2048, 8192, 8192, 2048, 0L, 0L, 0L, 0L, 8, 0);
  reduce_ep<<<dim3(1024), blk, 0, stream>>>(PART, b_d0, Z0,
      8, 2048, 2048, 0L, 0L, 1, 128*2048, 1);
  // Z1 = tanh(Z0 @ W_dmid[0] + b_dmid[0])
  gemm_mfma<2><<<dim3(32,1,8), blk, 0, stream>>>(Z0, W_dmid, b_dmid, Z1, PART,
      2048, 2048, 2048, 2048, 0L, 0L, 0L, 0L, 8, 0);
  reduce_ep<<<dim3(1024), blk, 0, stream>>>(PART, b_dmid, Z1,
      8, 2048, 2048, 0L, 0L, 1, 128*2048, 1);
  // Z2 = tanh(Z1 @ W_dmid[1] + b_dmid[1])
  gemm_mfma<2><<<dim3(32,1,8), blk, 0, stream>>>(Z1, W_dmid + 4194304, b_dmid + 2048, Z2, PART,
      2048, 2048, 2048, 2048, 0L, 0L, 0L, 0L, 8, 0);
  reduce_ep<<<dim3(1024), blk, 0, stream>>>(PART, b_dmid + 2048, Z2,
      8, 2048, 2048, 0L, 0L, 1, 128*2048, 1);
  // Y = Z2 @ W_dout + b_dout -> d_out [1,128,1024]
  gemm_mfma<1><<<dim3(32,1,8), blk, 0, stream>>>(Z2, W_dout, b_dout, (float*)d_out, PART,
      1024, 2048, 2048, 1024, 0L, 0L, 0L, 0L, 8, 0);
  reduce_ep<<<dim3(512), blk, 0, stream>>>(PART, b_dout, (float*)d_out,
      8, 1024, 1024, 0L, 0L, 0, 128*1024, 1);
}